// Round 7
// baseline (131.221 us; speedup 1.0000x reference)
//
#include <hip/hip_runtime.h>
#include <math.h>

#define CCH 64
#define NVOX 4096
#define NB 2
#define TS 136   // epilogue transpose row stride in halves (128 data + 8 pad)

typedef _Float16 f16x8 __attribute__((ext_vector_type(8)));
typedef _Float16 f16x4 __attribute__((ext_vector_type(4)));
typedef __fp16   g16x2 __attribute__((ext_vector_type(2)));  // cvt_pkrtz result type
typedef float f32x4 __attribute__((ext_vector_type(4)));

// ---------------- Kernel A: fused QKV projection ----------------
// x: [B, C, N] fp32; W*: [C, C] (out, in); b*: [C]
// qh, kh: [B, N, C] f16 ; vh: [B, C, N] f16
__global__ __launch_bounds__(256) void qkv_proj(
    const float* __restrict__ x,
    const float* __restrict__ Wq, const float* __restrict__ bq,
    const float* __restrict__ Wk, const float* __restrict__ bk,
    const float* __restrict__ Wv, const float* __restrict__ bv,
    _Float16* __restrict__ qh, _Float16* __restrict__ kh, _Float16* __restrict__ vh)
{
    __shared__ float Ws[3 * 64 * 64];   // 48 KB
    __shared__ float xs[64 * 32];       // 8 KB
    const int t  = threadIdx.x;
    const int b  = blockIdx.x >> 7;          // 128 tiles of 32 voxels per batch
    const int i0 = (blockIdx.x & 127) * 32;

    {
        const float4* Wq4 = (const float4*)Wq;
        const float4* Wk4 = (const float4*)Wk;
        const float4* Wv4 = (const float4*)Wv;
        float4* Ws4 = (float4*)Ws;
#pragma unroll
        for (int s = 0; s < 4; ++s) {
            int idx = t + 256 * s;
            Ws4[idx]        = Wq4[idx];
            Ws4[1024 + idx] = Wk4[idx];
            Ws4[2048 + idx] = Wv4[idx];
        }
    }
    {
        int cc = t >> 2;
        int m0 = (t & 3) * 8;
        const float* src = x + ((b * CCH + cc) * NVOX) + i0 + m0;
#pragma unroll
        for (int s = 0; s < 8; ++s) xs[cc * 32 + m0 + s] = src[s];
    }
    __syncthreads();

    const int vox = t & 31;
    const int c0  = (t >> 5) * 8;

#pragma unroll
    for (int m = 0; m < 3; ++m) {
        const float* Wm  = &Ws[m * 4096];
        const float* bia = (m == 0) ? bq : (m == 1) ? bk : bv;
        float acc[8];
#pragma unroll
        for (int j = 0; j < 8; ++j) acc[j] = bia[c0 + j];
        for (int cc = 0; cc < 64; cc += 4) {
            float xv0 = xs[(cc + 0) * 32 + vox];
            float xv1 = xs[(cc + 1) * 32 + vox];
            float xv2 = xs[(cc + 2) * 32 + vox];
            float xv3 = xs[(cc + 3) * 32 + vox];
#pragma unroll
            for (int j = 0; j < 8; ++j) {
                float4 w = *(const float4*)&Wm[(c0 + j) * 64 + cc];
                acc[j] = fmaf(w.x, xv0, acc[j]);
                acc[j] = fmaf(w.y, xv1, acc[j]);
                acc[j] = fmaf(w.z, xv2, acc[j]);
                acc[j] = fmaf(w.w, xv3, acc[j]);
            }
        }
        if (m < 2) {
            f16x8 hv;
#pragma unroll
            for (int j = 0; j < 8; ++j) hv[j] = (_Float16)acc[j];
            _Float16* dst = ((m == 0) ? qh : kh) + ((b * NVOX) + i0 + vox) * CCH + c0;
            *(f16x8*)dst = hv;
        } else {
#pragma unroll
            for (int j = 0; j < 8; ++j)
                vh[(b * CCH + c0 + j) * NVOX + i0 + vox] = (_Float16)acc[j];
        }
    }
}

// ---------------- Kernel B: MFMA flash attention (register fragments, no K-loop LDS) ----------------
// Block: 128-row i-tile (4 waves x 32 rows), 1/SPLIT of j range.
// K/V fragments load straight from global (L1/L2-resident) with 2-deep register
// prefetch; no __syncthreads in the hot loop. LDS used only for the epilogue transpose.
template <int SPLIT>
__global__ __launch_bounds__(256) void attn(
    const _Float16* __restrict__ qh, const _Float16* __restrict__ kh,
    const _Float16* __restrict__ vh,
    _Float16* __restrict__ po,  // [B*SPLIT][64][N] unnormalized O^T partials (f16)
    float* __restrict__ ml,     // [B*SPLIT][N][2] (m, l)
    float* __restrict__ out)    // [B][C][N]
{
    __shared__ _Float16 tb[64 * TS];   // epilogue transpose only (17408 B)

    constexpr int LS = (SPLIT == 8) ? 3 : (SPLIT == 4) ? 2 : (SPLIT == 2) ? 1 : 0;
    const int t    = threadIdx.x;
    const int h    = blockIdx.x & (SPLIT - 1);
    const int tile = blockIdx.x >> LS;
    const int b    = tile >> 5;          // 32 tiles of 128 rows per batch
    const int i0   = (tile & 31) * 128;

    const int lane = t & 63;
    const int w    = t >> 6;         // wave id: rows [w*32, w*32+32)
    const int q4   = lane >> 4;      // quad id
    const int n    = lane & 15;      // row within group: i = i0 + w*32 + g*16 + n

    const int JT = 64 / SPLIT;
    const _Float16* kbase = kh + (size_t)b * NVOX * CCH;
    const _Float16* vbase = vh + (size_t)b * CCH * NVOX;

    // Q B-operand fragments for both 16-row groups
    f16x8 aq[2][2];
#pragma unroll
    for (int g = 0; g < 2; ++g) {
        const _Float16* qrow =
            qh + ((size_t)(b * NVOX) + i0 + w * 32 + g * 16 + n) * CCH + q4 * 8;
        aq[g][0] = *(const f16x8*)(qrow);
        aq[g][1] = *(const f16x8*)(qrow + 32);
    }

    float m_prev[2] = {-1e30f, -1e30f}, l[2] = {0.f, 0.f};
    f32x4 o[2][4];
#pragma unroll
    for (int g = 0; g < 2; ++g)
#pragma unroll
        for (int mt = 0; mt < 4; ++mt) o[g][mt] = (f32x4){0.f, 0.f, 0.f, 0.f};

    // register fragment buffers (double-buffered across j-tiles)
    f16x8 ak0[2][4], ak1[2][4];
    f16x4 av0[4][4], av1[4][4];

    auto load_tile = [&](int jt, f16x8 (&ak)[2][4], f16x4 (&av)[4][4]) {
        const int j0 = (h * JT + jt) * 64;
        // K: ak[ks][nt] = K[j = j0+nt*16+n][c = ks*32+q4*8 ..+8]  (wave-coalesced 16B)
#pragma unroll
        for (int ks = 0; ks < 2; ++ks)
#pragma unroll
            for (int nt = 0; nt < 4; ++nt)
                ak[ks][nt] = *(const f16x8*)&kbase[(size_t)(j0 + nt * 16 + n) * CCH + ks * 32 + q4 * 8];
        // V: av[nt][mt] = V^T[c = mt*16+n][j = j0+nt*16+q4*4 ..+4]  (8B)
#pragma unroll
        for (int nt = 0; nt < 4; ++nt)
#pragma unroll
            for (int mt = 0; mt < 4; ++mt)
                av[nt][mt] = *(const f16x4*)&vbase[(size_t)(mt * 16 + n) * NVOX + j0 + nt * 16 + q4 * 4];
    };

    auto compute_tile = [&](const f16x8 (&ak)[2][4], const f16x4 (&av)[4][4]) {
        // S^T = K Q^T for both groups; K fragments shared
        f32x4 s[2][4];
#pragma unroll
        for (int g = 0; g < 2; ++g)
#pragma unroll
            for (int nt = 0; nt < 4; ++nt) s[g][nt] = (f32x4){0.f, 0.f, 0.f, 0.f};
#pragma unroll
        for (int ks = 0; ks < 2; ++ks)
#pragma unroll
            for (int nt = 0; nt < 4; ++nt) {
                s[0][nt] = __builtin_amdgcn_mfma_f32_16x16x32_f16(ak[ks][nt], aq[0][ks], s[0][nt], 0, 0, 0);
                s[1][nt] = __builtin_amdgcn_mfma_f32_16x16x32_f16(ak[ks][nt], aq[1][ks], s[1][nt], 0, 0, 0);
            }

        f16x4 bp[2][4];
        float alpha[2];
#pragma unroll
        for (int g = 0; g < 2; ++g) {
            float mx = -1e30f;
#pragma unroll
            for (int nt = 0; nt < 4; ++nt)
#pragma unroll
                for (int r = 0; r < 4; ++r) mx = fmaxf(mx, s[g][nt][r]);
            mx = fmaxf(mx, __shfl_xor(mx, 16, 64));
            mx = fmaxf(mx, __shfl_xor(mx, 32, 64));
            const float mn = fmaxf(m_prev[g], mx);

            float p[4][4], sum = 0.f;
#pragma unroll
            for (int nt = 0; nt < 4; ++nt)
#pragma unroll
                for (int r = 0; r < 4; ++r) {
                    p[nt][r] = __expf(s[g][nt][r] - mn);
                    sum += p[nt][r];
                }
            sum += __shfl_xor(sum, 16, 64);
            sum += __shfl_xor(sum, 32, 64);

            alpha[g]  = __expf(m_prev[g] - mn);
            l[g]      = l[g] * alpha[g] + sum;
            m_prev[g] = mn;

#pragma unroll
            for (int nt = 0; nt < 4; ++nt) {
                union { g16x2 g2[2]; f16x4 h4; } u;
                u.g2[0] = __builtin_amdgcn_cvt_pkrtz(p[nt][0], p[nt][1]);
                u.g2[1] = __builtin_amdgcn_cvt_pkrtz(p[nt][2], p[nt][3]);
                bp[g][nt] = u.h4;
            }
        }

#pragma unroll
        for (int g = 0; g < 2; ++g)
#pragma unroll
            for (int mt = 0; mt < 4; ++mt)
#pragma unroll
                for (int r = 0; r < 4; ++r) o[g][mt][r] *= alpha[g];

        // O^T += V^T P^T ; V fragments shared across groups
#pragma unroll
        for (int nt = 0; nt < 4; ++nt)
#pragma unroll
            for (int mt = 0; mt < 4; ++mt) {
                o[0][mt] = __builtin_amdgcn_mfma_f32_16x16x16f16(av[nt][mt], bp[0][nt], o[0][mt], 0, 0, 0);
                o[1][mt] = __builtin_amdgcn_mfma_f32_16x16x16f16(av[nt][mt], bp[1][nt], o[1][mt], 0, 0, 0);
            }
    };

    load_tile(0, ak0, av0);
    for (int jt = 0; jt < JT; jt += 2) {
        if (jt + 1 < JT) load_tile(jt + 1, ak1, av1);
        compute_tile(ak0, av0);
        if (jt + 2 < JT) load_tile(jt + 2, ak0, av0);
        if (jt + 1 < JT) compute_tile(ak1, av1);
    }

    if (SPLIT > 1) {
        // epilogue: transpose O^T through LDS for coalesced f16 stores
#pragma unroll
        for (int g = 0; g < 2; ++g)
#pragma unroll
            for (int mt = 0; mt < 4; ++mt)
#pragma unroll
                for (int r = 0; r < 4; ++r)
                    tb[(mt * 16 + q4 * 4 + r) * TS + w * 32 + g * 16 + n] =
                        (_Float16)o[g][mt][r];
#pragma unroll
        for (int g = 0; g < 2; ++g) {
            if (q4 == 0) {
                const int ig = i0 + w * 32 + g * 16 + n;
                float2* mlp = (float2*)&ml[((size_t)(b * SPLIT + h) * NVOX + ig) * 2];
                *mlp = make_float2(m_prev[g], l[g]);
            }
        }
        __syncthreads();
        const int cr = t >> 2;                 // 0..63 output channel row
        const int ib = (t & 3) * 32;           // i-chunk base within 128
        const size_t base = ((size_t)(b * SPLIT + h) * 64 + cr) * NVOX + i0 + ib;
#pragma unroll
        for (int u = 0; u < 4; ++u) {
            f16x8 vv = *(const f16x8*)&tb[cr * TS + ib + u * 8];
            *(f16x8*)&po[base + u * 8] = vv;
        }
    } else {
#pragma unroll
        for (int g = 0; g < 2; ++g) {
            const int ig = i0 + w * 32 + g * 16 + n;
            const float inv = 1.0f / l[g];
#pragma unroll
            for (int mt = 0; mt < 4; ++mt)
#pragma unroll
                for (int r = 0; r < 4; ++r)
                    out[(size_t)(b * CCH + mt * 16 + q4 * 4 + r) * NVOX + ig] =
                        o[g][mt][r] * inv;
        }
    }
}

// ---------------- Kernel C: combine split-j partials (f16 partials) ----------------
template <int SPLIT>
__global__ __launch_bounds__(256) void combine(
    const _Float16* __restrict__ po, const float* __restrict__ ml,
    float* __restrict__ out)
{
    __shared__ float wls[SPLIT * 64];
    const int t  = threadIdx.x;
    const int b  = blockIdx.x >> 6;
    const int i0 = (blockIdx.x & 63) * 64;

    if (t < 64) {
        const int i = i0 + t;
        float mv[SPLIT], lv[SPLIT], M = -1e30f;
#pragma unroll
        for (int h = 0; h < SPLIT; ++h) {
            mv[h] = ml[((size_t)(b * SPLIT + h) * NVOX + i) * 2 + 0];
            lv[h] = ml[((size_t)(b * SPLIT + h) * NVOX + i) * 2 + 1];
            M = fmaxf(M, mv[h]);
        }
        float den = 0.f;
#pragma unroll
        for (int h = 0; h < SPLIT; ++h) den += lv[h] * __expf(mv[h] - M);
        const float inv = 1.0f / den;
#pragma unroll
        for (int h = 0; h < SPLIT; ++h) wls[h * 64 + t] = __expf(mv[h] - M) * inv;
    }
    __syncthreads();

    const int c  = t >> 2;
    const int iq = t & 3;
    float acc[16];
#pragma unroll
    for (int u = 0; u < 16; ++u) acc[u] = 0.f;
#pragma unroll
    for (int h = 0; h < SPLIT; ++h) {
        const f16x8* src = (const f16x8*)&po[((size_t)(b * SPLIT + h) * 64 + c) * NVOX + i0 + iq * 16];
        const float* wp  = &wls[h * 64 + iq * 16];
#pragma unroll
        for (int u = 0; u < 2; ++u) {
            f16x8 f = src[u];
#pragma unroll
            for (int e = 0; e < 8; ++e)
                acc[u * 8 + e] = fmaf((float)f[e], wp[u * 8 + e], acc[u * 8 + e]);
        }
    }
    float4* dst = (float4*)&out[(size_t)(b * CCH + c) * NVOX + i0 + iq * 16];
#pragma unroll
    for (int u = 0; u < 4; ++u)
        dst[u] = make_float4(acc[u * 4], acc[u * 4 + 1], acc[u * 4 + 2], acc[u * 4 + 3]);
}

extern "C" void kernel_launch(void* const* d_in, const int* in_sizes, int n_in,
                              void* d_out, int out_size, void* d_ws, size_t ws_size,
                              hipStream_t stream)
{
    const float* x  = (const float*)d_in[0];
    const float* Wq = (const float*)d_in[1];
    const float* bq = (const float*)d_in[2];
    const float* Wk = (const float*)d_in[3];
    const float* bk = (const float*)d_in[4];
    const float* Wv = (const float*)d_in[5];
    const float* bv = (const float*)d_in[6];
    float* out = (float*)d_out;

    _Float16* qh = (_Float16*)d_ws;                 // B*N*C halves
    _Float16* kh = qh + NB * NVOX * CCH;
    _Float16* vh = kh + NB * NVOX * CCH;
    _Float16* po = vh + NB * NVOX * CCH;            // B*SPLIT*64*N halves
    const size_t qkv_bytes = (size_t)3 * NB * NVOX * CCH * sizeof(_Float16);

    qkv_proj<<<NB * (NVOX / 32), 256, 0, stream>>>(x, Wq, bq, Wk, bk, Wv, bv, qh, kh, vh);

    const size_t need8 = qkv_bytes +
        (size_t)NB * 8 * 64 * NVOX * sizeof(_Float16) + (size_t)NB * 8 * NVOX * 2 * sizeof(float);
    const size_t need4 = qkv_bytes +
        (size_t)NB * 4 * 64 * NVOX * sizeof(_Float16) + (size_t)NB * 4 * NVOX * 2 * sizeof(float);
    const size_t need2 = qkv_bytes +
        (size_t)NB * 2 * 64 * NVOX * sizeof(_Float16) + (size_t)NB * 2 * NVOX * 2 * sizeof(float);

    if (ws_size >= need8) {
        float* ml = (float*)(po + (size_t)NB * 8 * 64 * NVOX);
        attn<8><<<NB * 32 * 8, 256, 0, stream>>>(qh, kh, vh, po, ml, out);
        combine<8><<<NB * 64, 256, 0, stream>>>(po, ml, out);
    } else if (ws_size >= need4) {
        float* ml = (float*)(po + (size_t)NB * 4 * 64 * NVOX);
        attn<4><<<NB * 32 * 4, 256, 0, stream>>>(qh, kh, vh, po, ml, out);
        combine<4><<<NB * 64, 256, 0, stream>>>(po, ml, out);
    } else if (ws_size >= need2) {
        float* ml = (float*)(po + (size_t)NB * 2 * 64 * NVOX);
        attn<2><<<NB * 32 * 2, 256, 0, stream>>>(qh, kh, vh, po, ml, out);
        combine<2><<<NB * 64, 256, 0, stream>>>(po, ml, out);
    } else {
        attn<1><<<NB * 32, 256, 0, stream>>>(qh, kh, vh, nullptr, nullptr, out);
    }
}

// Round 9
// 117.410 us; speedup vs baseline: 1.1176x; 1.1176x over previous
//
#include <hip/hip_runtime.h>
#include <math.h>

#define CCH 64
#define NVOX 4096
#define NB 2
#define VRS 72   // V LDS row stride in halves (64 data + 8 pad) -> 2-way (free)
#define TS 136   // epilogue transpose row stride in halves (128 data + 8 pad)

typedef _Float16 f16x8 __attribute__((ext_vector_type(8)));
typedef _Float16 f16x4 __attribute__((ext_vector_type(4)));
typedef __fp16   g16x2 __attribute__((ext_vector_type(2)));  // cvt_pkrtz result type
typedef float f32x4 __attribute__((ext_vector_type(4)));

// ---------------- Kernel A: fused QKV projection ----------------
// x: [B, C, N] fp32; W*: [C, C] (out, in); b*: [C]
// qh, kh: [B, N, C] f16 ; vh: [B, C, N] f16
__global__ __launch_bounds__(256) void qkv_proj(
    const float* __restrict__ x,
    const float* __restrict__ Wq, const float* __restrict__ bq,
    const float* __restrict__ Wk, const float* __restrict__ bk,
    const float* __restrict__ Wv, const float* __restrict__ bv,
    _Float16* __restrict__ qh, _Float16* __restrict__ kh, _Float16* __restrict__ vh)
{
    __shared__ float Ws[3 * 64 * 64];   // 48 KB
    __shared__ float xs[64 * 32];       // 8 KB
    const int t  = threadIdx.x;
    const int b  = blockIdx.x >> 7;          // 128 tiles of 32 voxels per batch
    const int i0 = (blockIdx.x & 127) * 32;

    {
        const float4* Wq4 = (const float4*)Wq;
        const float4* Wk4 = (const float4*)Wk;
        const float4* Wv4 = (const float4*)Wv;
        float4* Ws4 = (float4*)Ws;
#pragma unroll
        for (int s = 0; s < 4; ++s) {
            int idx = t + 256 * s;
            Ws4[idx]        = Wq4[idx];
            Ws4[1024 + idx] = Wk4[idx];
            Ws4[2048 + idx] = Wv4[idx];
        }
    }
    {
        int cc = t >> 2;
        int m0 = (t & 3) * 8;
        const float* src = x + ((b * CCH + cc) * NVOX) + i0 + m0;
#pragma unroll
        for (int s = 0; s < 8; ++s) xs[cc * 32 + m0 + s] = src[s];
    }
    __syncthreads();

    const int vox = t & 31;
    const int c0  = (t >> 5) * 8;

#pragma unroll
    for (int m = 0; m < 3; ++m) {
        const float* Wm  = &Ws[m * 4096];
        const float* bia = (m == 0) ? bq : (m == 1) ? bk : bv;
        float acc[8];
#pragma unroll
        for (int j = 0; j < 8; ++j) acc[j] = bia[c0 + j];
        for (int cc = 0; cc < 64; cc += 4) {
            float xv0 = xs[(cc + 0) * 32 + vox];
            float xv1 = xs[(cc + 1) * 32 + vox];
            float xv2 = xs[(cc + 2) * 32 + vox];
            float xv3 = xs[(cc + 3) * 32 + vox];
#pragma unroll
            for (int j = 0; j < 8; ++j) {
                float4 w = *(const float4*)&Wm[(c0 + j) * 64 + cc];
                acc[j] = fmaf(w.x, xv0, acc[j]);
                acc[j] = fmaf(w.y, xv1, acc[j]);
                acc[j] = fmaf(w.z, xv2, acc[j]);
                acc[j] = fmaf(w.w, xv3, acc[j]);
            }
        }
        if (m < 2) {
            f16x8 hv;
#pragma unroll
            for (int j = 0; j < 8; ++j) hv[j] = (_Float16)acc[j];
            _Float16* dst = ((m == 0) ? qh : kh) + ((b * NVOX) + i0 + vox) * CCH + c0;
            *(f16x8*)dst = hv;
        } else {
#pragma unroll
            for (int j = 0; j < 8; ++j)
                vh[(b * CCH + c0 + j) * NVOX + i0 + vox] = (_Float16)acc[j];
        }
    }
}

// ---------------- Kernel B: MFMA flash attention ----------------
// Block: 128-row i-tile (4 waves x 32 rows), 1/SPLIT of j range, double-buffered LDS.
// K buffer is XOR-swizzled (chunk ^= j&7), unpadded -> conflict-free ds_read_b128.
// V buffer padded (+8 halves) -> 2-way (free). Deferred l-reduction (epilogue only).
template <int SPLIT>
__global__ __launch_bounds__(256, 3) void attn(
    const _Float16* __restrict__ qh, const _Float16* __restrict__ kh,
    const _Float16* __restrict__ vh,
    _Float16* __restrict__ po,  // [B*SPLIT][64][N] unnormalized O^T partials (f16)
    float* __restrict__ ml,     // [B*SPLIT][N][2] (m, l)
    float* __restrict__ out)    // [B][C][N]
{
    __shared__ _Float16 smem[2 * 64 * 64 + 2 * 64 * VRS];  // 34816 B

    constexpr int LS = (SPLIT == 16) ? 4 : (SPLIT == 8) ? 3 :
                       (SPLIT == 4) ? 2 : (SPLIT == 2) ? 1 : 0;
    const int t    = threadIdx.x;
    const int h    = blockIdx.x & (SPLIT - 1);
    const int tile = blockIdx.x >> LS;
    const int b    = tile >> 5;          // 32 tiles of 128 rows per batch
    const int i0   = (tile & 31) * 128;

    const int lane = t & 63;
    const int w    = t >> 6;         // wave id: rows [w*32, w*32+32)
    const int q4   = lane >> 4;      // quad id
    const int n    = lane & 15;      // row within group: i = i0 + w*32 + g*16 + n
    const int nx   = n & 7;

    auto kb = [&](int buf) -> _Float16* { return smem + buf * 4096; };
    auto vb = [&](int buf) -> _Float16* { return smem + 8192 + buf * 64 * VRS; };

    const int row = t >> 2;          // staging row 0..63
    const int c2  = t & 3;           // staging 16-half column group
    const int JT  = 64 / SPLIT;

    auto load_tile = [&](int jt, float4 r[4]) {
        const int j0 = (h * JT + jt) * 64;
        const float4* ks = (const float4*)&kh[((size_t)(b * NVOX) + j0 + row) * CCH + c2 * 16];
        r[0] = ks[0]; r[1] = ks[1];
        const float4* vs = (const float4*)&vh[((size_t)b * CCH + row) * NVOX + j0 + c2 * 16];
        r[2] = vs[0]; r[3] = vs[1];
    };
    auto store_tile = [&](int buf, const float4 r[4]) {
        const int rx = row & 7;
        *(float4*)&kb(buf)[row * 64 + ((2 * c2) ^ rx) * 8]     = r[0];
        *(float4*)&kb(buf)[row * 64 + ((2 * c2 + 1) ^ rx) * 8] = r[1];
        *(float4*)&vb(buf)[row * VRS + c2 * 16]     = r[2];
        *(float4*)&vb(buf)[row * VRS + c2 * 16 + 8] = r[3];
    };

    // Q B-operand fragments for both 16-row groups, straight from global
    f16x8 aq[2][2];
#pragma unroll
    for (int g = 0; g < 2; ++g) {
        const _Float16* qrow =
            qh + ((size_t)(b * NVOX) + i0 + w * 32 + g * 16 + n) * CCH + q4 * 8;
        aq[g][0] = *(const f16x8*)(qrow);
        aq[g][1] = *(const f16x8*)(qrow + 32);
    }

    float4 stg[4];
    load_tile(0, stg);
    store_tile(0, stg);

    float m_prev[2] = {-1e30f, -1e30f}, l[2] = {0.f, 0.f};
    f32x4 o[2][4];
#pragma unroll
    for (int g = 0; g < 2; ++g)
#pragma unroll
        for (int mt = 0; mt < 4; ++mt) o[g][mt] = (f32x4){0.f, 0.f, 0.f, 0.f};

    __syncthreads();

    for (int jt = 0; jt < JT; ++jt) {
        const int buf = jt & 1;
        if (jt + 1 < JT) load_tile(jt + 1, stg);   // in flight during compute

        // S^T = K Q^T for both groups; K fragments read once, used twice
        f32x4 s[2][4];
#pragma unroll
        for (int g = 0; g < 2; ++g)
#pragma unroll
            for (int nt = 0; nt < 4; ++nt) s[g][nt] = (f32x4){0.f, 0.f, 0.f, 0.f};
#pragma unroll
        for (int ks = 0; ks < 2; ++ks)
#pragma unroll
            for (int nt = 0; nt < 4; ++nt) {
                f16x8 ak = *(const f16x8*)&kb(buf)[(nt * 16 + n) * 64 +
                                                   (((ks * 4 + q4) ^ nx) * 8)];
                s[0][nt] = __builtin_amdgcn_mfma_f32_16x16x32_f16(ak, aq[0][ks], s[0][nt], 0, 0, 0);
                s[1][nt] = __builtin_amdgcn_mfma_f32_16x16x32_f16(ak, aq[1][ks], s[1][nt], 0, 0, 0);
            }

        // per-lane online softmax; l kept as per-lane partial (reduced in epilogue)
        f16x4 bp[2][4];
        float alpha[2];
#pragma unroll
        for (int g = 0; g < 2; ++g) {
            float mx = -1e30f;
#pragma unroll
            for (int nt = 0; nt < 4; ++nt)
#pragma unroll
                for (int r = 0; r < 4; ++r) mx = fmaxf(mx, s[g][nt][r]);
            mx = fmaxf(mx, __shfl_xor(mx, 16, 64));
            mx = fmaxf(mx, __shfl_xor(mx, 32, 64));
            const float mn = fmaxf(m_prev[g], mx);

            float p[4][4], sum = 0.f;
#pragma unroll
            for (int nt = 0; nt < 4; ++nt)
#pragma unroll
                for (int r = 0; r < 4; ++r) {
                    p[nt][r] = __expf(s[g][nt][r] - mn);
                    sum += p[nt][r];
                }
            alpha[g]  = __expf(m_prev[g] - mn);
            l[g]      = l[g] * alpha[g] + sum;
            m_prev[g] = mn;

#pragma unroll
            for (int nt = 0; nt < 4; ++nt) {
                union { g16x2 g2[2]; f16x4 h4; } u;
                u.g2[0] = __builtin_amdgcn_cvt_pkrtz(p[nt][0], p[nt][1]);
                u.g2[1] = __builtin_amdgcn_cvt_pkrtz(p[nt][2], p[nt][3]);
                bp[g][nt] = u.h4;
            }
        }

#pragma unroll
        for (int g = 0; g < 2; ++g)
#pragma unroll
            for (int mt = 0; mt < 4; ++mt)
#pragma unroll
                for (int r = 0; r < 4; ++r) o[g][mt][r] *= alpha[g];

        // O^T += V^T P^T ; V fragments read once, used for both groups
#pragma unroll
        for (int nt = 0; nt < 4; ++nt)
#pragma unroll
            for (int mt = 0; mt < 4; ++mt) {
                f16x4 av = *(const f16x4*)&vb(buf)[(mt * 16 + n) * VRS + nt * 16 + q4 * 4];
                o[0][mt] = __builtin_amdgcn_mfma_f32_16x16x16f16(av, bp[0][nt], o[0][mt], 0, 0, 0);
                o[1][mt] = __builtin_amdgcn_mfma_f32_16x16x16f16(av, bp[1][nt], o[1][mt], 0, 0, 0);
            }

        if (jt + 1 < JT) {
            __syncthreads();               // all waves done reading buf^1 (tile jt-1)
            store_tile(buf ^ 1, stg);
            __syncthreads();               // tile jt+1 visible
        }
    }

    // deferred l reduction across the 4 quads (m is already quad-uniform)
    float l_tot[2];
#pragma unroll
    for (int g = 0; g < 2; ++g) {
        float lv = l[g];
        lv += __shfl_xor(lv, 16, 64);
        lv += __shfl_xor(lv, 32, 64);
        l_tot[g] = lv;
    }

    if (SPLIT > 1) {
        __syncthreads();                       // everyone done with kb/vb
        _Float16* tb = smem;                   // 64 x TS halves = 17408 B
#pragma unroll
        for (int g = 0; g < 2; ++g)
#pragma unroll
            for (int mt = 0; mt < 4; ++mt)
#pragma unroll
                for (int r = 0; r < 4; ++r)
                    tb[(mt * 16 + q4 * 4 + r) * TS + w * 32 + g * 16 + n] =
                        (_Float16)o[g][mt][r];
#pragma unroll
        for (int g = 0; g < 2; ++g) {
            if (q4 == 0) {
                const int ig = i0 + w * 32 + g * 16 + n;
                float2* mlp = (float2*)&ml[((size_t)(b * SPLIT + h) * NVOX + ig) * 2];
                *mlp = make_float2(m_prev[g], l_tot[g]);
            }
        }
        __syncthreads();
        const int cr = t >> 2;                 // 0..63 output channel row
        const int ib = (t & 3) * 32;           // i-chunk base within 128
        const size_t base = ((size_t)(b * SPLIT + h) * 64 + cr) * NVOX + i0 + ib;
#pragma unroll
        for (int u = 0; u < 4; ++u) {
            f16x8 vv = *(const f16x8*)&tb[cr * TS + ib + u * 8];
            *(f16x8*)&po[base + u * 8] = vv;
        }
    } else {
#pragma unroll
        for (int g = 0; g < 2; ++g) {
            const int ig = i0 + w * 32 + g * 16 + n;
            const float inv = 1.0f / l_tot[g];
#pragma unroll
            for (int mt = 0; mt < 4; ++mt)
#pragma unroll
                for (int r = 0; r < 4; ++r)
                    out[(size_t)(b * CCH + mt * 16 + q4 * 4 + r) * NVOX + ig] =
                        o[g][mt][r] * inv;
        }
    }
}

// ---------------- Kernel C: combine split-j partials (f16 partials) ----------------
template <int SPLIT>
__global__ __launch_bounds__(256) void combine(
    const _Float16* __restrict__ po, const float* __restrict__ ml,
    float* __restrict__ out)
{
    __shared__ float wls[SPLIT * 64];
    const int t  = threadIdx.x;
    const int b  = blockIdx.x >> 6;
    const int i0 = (blockIdx.x & 63) * 64;

    if (t < 64) {
        const int i = i0 + t;
        float mv[SPLIT], lv[SPLIT], M = -1e30f;
#pragma unroll
        for (int h = 0; h < SPLIT; ++h) {
            mv[h] = ml[((size_t)(b * SPLIT + h) * NVOX + i) * 2 + 0];
            lv[h] = ml[((size_t)(b * SPLIT + h) * NVOX + i) * 2 + 1];
            M = fmaxf(M, mv[h]);
        }
        float den = 0.f;
#pragma unroll
        for (int h = 0; h < SPLIT; ++h) den += lv[h] * __expf(mv[h] - M);
        const float inv = 1.0f / den;
#pragma unroll
        for (int h = 0; h < SPLIT; ++h) wls[h * 64 + t] = __expf(mv[h] - M) * inv;
    }
    __syncthreads();

    const int c  = t >> 2;
    const int iq = t & 3;
    float acc[16];
#pragma unroll
    for (int u = 0; u < 16; ++u) acc[u] = 0.f;
#pragma unroll
    for (int h = 0; h < SPLIT; ++h) {
        const f16x8* src = (const f16x8*)&po[((size_t)(b * SPLIT + h) * 64 + c) * NVOX + i0 + iq * 16];
        const float* wp  = &wls[h * 64 + iq * 16];
#pragma unroll
        for (int u = 0; u < 2; ++u) {
            f16x8 f = src[u];
#pragma unroll
            for (int e = 0; e < 8; ++e)
                acc[u * 8 + e] = fmaf((float)f[e], wp[u * 8 + e], acc[u * 8 + e]);
        }
    }
    float4* dst = (float4*)&out[(size_t)(b * CCH + c) * NVOX + i0 + iq * 16];
#pragma unroll
    for (int u = 0; u < 4; ++u)
        dst[u] = make_float4(acc[u * 4], acc[u * 4 + 1], acc[u * 4 + 2], acc[u * 4 + 3]);
}

extern "C" void kernel_launch(void* const* d_in, const int* in_sizes, int n_in,
                              void* d_out, int out_size, void* d_ws, size_t ws_size,
                              hipStream_t stream)
{
    const float* x  = (const float*)d_in[0];
    const float* Wq = (const float*)d_in[1];
    const float* bq = (const float*)d_in[2];
    const float* Wk = (const float*)d_in[3];
    const float* bk = (const float*)d_in[4];
    const float* Wv = (const float*)d_in[5];
    const float* bv = (const float*)d_in[6];
    float* out = (float*)d_out;

    _Float16* qh = (_Float16*)d_ws;                 // B*N*C halves
    _Float16* kh = qh + NB * NVOX * CCH;
    _Float16* vh = kh + NB * NVOX * CCH;
    _Float16* po = vh + NB * NVOX * CCH;            // B*SPLIT*64*N halves
    const size_t qkv_bytes = (size_t)3 * NB * NVOX * CCH * sizeof(_Float16);

    qkv_proj<<<NB * (NVOX / 32), 256, 0, stream>>>(x, Wq, bq, Wk, bk, Wv, bv, qh, kh, vh);

    auto need = [&](int sp) {
        return qkv_bytes + (size_t)NB * sp * 64 * NVOX * sizeof(_Float16)
                         + (size_t)NB * sp * NVOX * 2 * sizeof(float);
    };

    if (ws_size >= need(16)) {
        float* ml = (float*)(po + (size_t)NB * 16 * 64 * NVOX);
        attn<16><<<NB * 32 * 16, 256, 0, stream>>>(qh, kh, vh, po, ml, out);
        combine<16><<<NB * 64, 256, 0, stream>>>(po, ml, out);
    } else if (ws_size >= need(8)) {
        float* ml = (float*)(po + (size_t)NB * 8 * 64 * NVOX);
        attn<8><<<NB * 32 * 8, 256, 0, stream>>>(qh, kh, vh, po, ml, out);
        combine<8><<<NB * 64, 256, 0, stream>>>(po, ml, out);
    } else if (ws_size >= need(4)) {
        float* ml = (float*)(po + (size_t)NB * 4 * 64 * NVOX);
        attn<4><<<NB * 32 * 4, 256, 0, stream>>>(qh, kh, vh, po, ml, out);
        combine<4><<<NB * 64, 256, 0, stream>>>(po, ml, out);
    } else if (ws_size >= need(2)) {
        float* ml = (float*)(po + (size_t)NB * 2 * 64 * NVOX);
        attn<2><<<NB * 32 * 2, 256, 0, stream>>>(qh, kh, vh, po, ml, out);
        combine<2><<<NB * 64, 256, 0, stream>>>(po, ml, out);
    } else {
        attn<1><<<NB * 32, 256, 0, stream>>>(qh, kh, vh, nullptr, nullptr, out);
    }
}

// Round 10
// 103.350 us; speedup vs baseline: 1.2697x; 1.1360x over previous
//
#include <hip/hip_runtime.h>
#include <math.h>

#define CCH 64
#define NVOX 4096
#define NB 2
#define TS 136   // epilogue transpose row stride in halves (128 data + 8 pad)

typedef _Float16 f16x8 __attribute__((ext_vector_type(8)));
typedef _Float16 f16x4 __attribute__((ext_vector_type(4)));
typedef __fp16   g16x2 __attribute__((ext_vector_type(2)));  // cvt_pkrtz result type
typedef float f32x4 __attribute__((ext_vector_type(4)));

// ---------------- Kernel A: fused QKV projection ----------------
// x: [B, C, N] fp32; W*: [C, C] (out, in); b*: [C]
// qh: [B, N, C] f16 (row-major)
// khf: MFMA A-frag tiles: chunk ((b*256 + j/16)*2 + ks)*64 + (q4*16 + n), 8 halves
//      element (lane=q4*16+n, jj) = K[j=(j/16)*16+n][c = ks*32 + q4*8 + jj]
// vhf: MFMA A-frag tiles (K=16): half idx (((b*256 + j/16)*4 + mt)*64 + q4*16 + n)*4 + r
//      = V^T[c = mt*16+n][j = (j/16)*16 + q4*4 + r]
__global__ __launch_bounds__(256) void qkv_proj(
    const float* __restrict__ x,
    const float* __restrict__ Wq, const float* __restrict__ bq,
    const float* __restrict__ Wk, const float* __restrict__ bk,
    const float* __restrict__ Wv, const float* __restrict__ bv,
    _Float16* __restrict__ qh, _Float16* __restrict__ khf, _Float16* __restrict__ vhf)
{
    __shared__ float Ws[3 * 64 * 64];   // 48 KB
    __shared__ float xs[64 * 32];       // 8 KB
    const int t  = threadIdx.x;
    const int b  = blockIdx.x >> 7;          // 128 tiles of 32 voxels per batch
    const int i0 = (blockIdx.x & 127) * 32;

    {
        const float4* Wq4 = (const float4*)Wq;
        const float4* Wk4 = (const float4*)Wk;
        const float4* Wv4 = (const float4*)Wv;
        float4* Ws4 = (float4*)Ws;
#pragma unroll
        for (int s = 0; s < 4; ++s) {
            int idx = t + 256 * s;
            Ws4[idx]        = Wq4[idx];
            Ws4[1024 + idx] = Wk4[idx];
            Ws4[2048 + idx] = Wv4[idx];
        }
    }
    {
        int cc = t >> 2;
        int m0 = (t & 3) * 8;
        const float* src = x + ((b * CCH + cc) * NVOX) + i0 + m0;
#pragma unroll
        for (int s = 0; s < 8; ++s) xs[cc * 32 + m0 + s] = src[s];
    }
    __syncthreads();

    const int vox = t & 31;
    const int c0  = (t >> 5) * 8;
    const int j   = i0 + vox;
    const int jb  = j >> 4;

#pragma unroll
    for (int m = 0; m < 3; ++m) {
        const float* Wm  = &Ws[m * 4096];
        const float* bia = (m == 0) ? bq : (m == 1) ? bk : bv;
        float acc[8];
#pragma unroll
        for (int jj = 0; jj < 8; ++jj) acc[jj] = bia[c0 + jj];
        for (int cc = 0; cc < 64; cc += 4) {
            float xv0 = xs[(cc + 0) * 32 + vox];
            float xv1 = xs[(cc + 1) * 32 + vox];
            float xv2 = xs[(cc + 2) * 32 + vox];
            float xv3 = xs[(cc + 3) * 32 + vox];
#pragma unroll
            for (int jj = 0; jj < 8; ++jj) {
                float4 w = *(const float4*)&Wm[(c0 + jj) * 64 + cc];
                acc[jj] = fmaf(w.x, xv0, acc[jj]);
                acc[jj] = fmaf(w.y, xv1, acc[jj]);
                acc[jj] = fmaf(w.z, xv2, acc[jj]);
                acc[jj] = fmaf(w.w, xv3, acc[jj]);
            }
        }
        if (m == 0) {
            f16x8 hv;
#pragma unroll
            for (int jj = 0; jj < 8; ++jj) hv[jj] = (_Float16)acc[jj];
            *(f16x8*)&qh[((size_t)(b * NVOX) + j) * CCH + c0] = hv;
        } else if (m == 1) {
            f16x8 hv;
#pragma unroll
            for (int jj = 0; jj < 8; ++jj) hv[jj] = (_Float16)acc[jj];
            const int ks = c0 >> 5, q4 = (c0 >> 3) & 3, n = j & 15;
            *(f16x8*)&khf[((((size_t)b * 256 + jb) * 2 + ks) * 64 + q4 * 16 + n) * 8] = hv;
        } else {
            const int q4v = (j >> 2) & 3, r = j & 3;
#pragma unroll
            for (int jj = 0; jj < 8; ++jj) {
                const int c = c0 + jj, mt = c >> 4, nch = c & 15;
                vhf[((((size_t)b * 256 + jb) * 4 + mt) * 64 + q4v * 16 + nch) * 4 + r] =
                    (_Float16)acc[jj];
            }
        }
    }
}

// ---------------- Kernel B: MFMA flash attention (fragment-layout global, no LDS K-loop) ----------------
// Block: 128-row i-tile (4 waves x 32 rows), 1/SPLIT of j range.
// K/V fragments load directly from global in MFMA layout — fully coalesced
// (chunk*64 + lane). K double-buffered one tile ahead; V issued at tile top,
// consumed after softmax. No __syncthreads in the hot loop.
template <int SPLIT>
__global__ __launch_bounds__(256) void attn(
    const _Float16* __restrict__ qh, const _Float16* __restrict__ khf,
    const _Float16* __restrict__ vhf,
    _Float16* __restrict__ po,  // [B*SPLIT][64][N] unnormalized O^T partials (f16)
    float* __restrict__ ml,     // [B*SPLIT][N][2] (m, l)
    float* __restrict__ out)    // [B][C][N]
{
    __shared__ _Float16 tb[64 * TS];   // epilogue transpose only (17408 B)

    constexpr int LS = (SPLIT == 8) ? 3 : (SPLIT == 4) ? 2 : (SPLIT == 2) ? 1 : 0;
    const int t    = threadIdx.x;
    const int h    = blockIdx.x & (SPLIT - 1);
    const int tile = blockIdx.x >> LS;
    const int b    = tile >> 5;          // 32 tiles of 128 rows per batch
    const int i0   = (tile & 31) * 128;

    const int lane = t & 63;
    const int w    = t >> 6;         // wave id: rows [w*32, w*32+32)
    const int q4   = lane >> 4;      // quad id
    const int n    = lane & 15;      // row within group: i = i0 + w*32 + g*16 + n

    const int JT = 64 / SPLIT;
    const f16x8* k8 = (const f16x8*)khf;
    const f16x4* v4 = (const f16x4*)vhf;

    // Q B-operand fragments for both 16-row groups
    f16x8 aq[2][2];
#pragma unroll
    for (int g = 0; g < 2; ++g) {
        const _Float16* qrow =
            qh + ((size_t)(b * NVOX) + i0 + w * 32 + g * 16 + n) * CCH + q4 * 8;
        aq[g][0] = *(const f16x8*)(qrow);
        aq[g][1] = *(const f16x8*)(qrow + 32);
    }

    float m_prev[2] = {-1e30f, -1e30f}, l[2] = {0.f, 0.f};
    f32x4 o[2][4];
#pragma unroll
    for (int g = 0; g < 2; ++g)
#pragma unroll
        for (int mt = 0; mt < 4; ++mt) o[g][mt] = (f32x4){0.f, 0.f, 0.f, 0.f};

    f16x8 akA[2][4], akB[2][4];
    f16x4 av[4][4];

    auto loadK = [&](int jt, f16x8 (&ak)[2][4]) {
        const size_t jb0 = (size_t)b * 256 + (h * JT + jt) * 4;
#pragma unroll
        for (int nt = 0; nt < 4; ++nt)
#pragma unroll
            for (int ks = 0; ks < 2; ++ks)
                ak[ks][nt] = k8[((jb0 + nt) * 2 + ks) * 64 + lane];
    };
    auto loadV = [&](int jt) {
        const size_t jb0 = (size_t)b * 256 + (h * JT + jt) * 4;
#pragma unroll
        for (int nt = 0; nt < 4; ++nt)
#pragma unroll
            for (int mt = 0; mt < 4; ++mt)
                av[nt][mt] = v4[((jb0 + nt) * 4 + mt) * 64 + lane];
    };

    auto compute_tile = [&](const f16x8 (&ak)[2][4]) {
        // S^T = K Q^T for both groups; K fragments shared
        f32x4 s[2][4];
#pragma unroll
        for (int g = 0; g < 2; ++g)
#pragma unroll
            for (int nt = 0; nt < 4; ++nt) s[g][nt] = (f32x4){0.f, 0.f, 0.f, 0.f};
#pragma unroll
        for (int ks = 0; ks < 2; ++ks)
#pragma unroll
            for (int nt = 0; nt < 4; ++nt) {
                s[0][nt] = __builtin_amdgcn_mfma_f32_16x16x32_f16(ak[ks][nt], aq[0][ks], s[0][nt], 0, 0, 0);
                s[1][nt] = __builtin_amdgcn_mfma_f32_16x16x32_f16(ak[ks][nt], aq[1][ks], s[1][nt], 0, 0, 0);
            }

        // per-lane online softmax; l kept per-lane (reduced in epilogue)
        f16x4 bp[2][4];
        float alpha[2];
#pragma unroll
        for (int g = 0; g < 2; ++g) {
            float mx = -1e30f;
#pragma unroll
            for (int nt = 0; nt < 4; ++nt)
#pragma unroll
                for (int r = 0; r < 4; ++r) mx = fmaxf(mx, s[g][nt][r]);
            mx = fmaxf(mx, __shfl_xor(mx, 16, 64));
            mx = fmaxf(mx, __shfl_xor(mx, 32, 64));
            const float mn = fmaxf(m_prev[g], mx);

            float p[4][4], sum = 0.f;
#pragma unroll
            for (int nt = 0; nt < 4; ++nt)
#pragma unroll
                for (int r = 0; r < 4; ++r) {
                    p[nt][r] = __expf(s[g][nt][r] - mn);
                    sum += p[nt][r];
                }
            alpha[g]  = __expf(m_prev[g] - mn);
            l[g]      = l[g] * alpha[g] + sum;
            m_prev[g] = mn;

#pragma unroll
            for (int nt = 0; nt < 4; ++nt) {
                union { g16x2 g2[2]; f16x4 h4; } u;
                u.g2[0] = __builtin_amdgcn_cvt_pkrtz(p[nt][0], p[nt][1]);
                u.g2[1] = __builtin_amdgcn_cvt_pkrtz(p[nt][2], p[nt][3]);
                bp[g][nt] = u.h4;
            }
        }

#pragma unroll
        for (int g = 0; g < 2; ++g)
#pragma unroll
            for (int mt = 0; mt < 4; ++mt)
#pragma unroll
                for (int r = 0; r < 4; ++r) o[g][mt][r] *= alpha[g];

        // O^T += V^T P^T ; V fragments shared across groups
#pragma unroll
        for (int nt = 0; nt < 4; ++nt)
#pragma unroll
            for (int mt = 0; mt < 4; ++mt) {
                o[0][mt] = __builtin_amdgcn_mfma_f32_16x16x16f16(av[nt][mt], bp[0][nt], o[0][mt], 0, 0, 0);
                o[1][mt] = __builtin_amdgcn_mfma_f32_16x16x16f16(av[nt][mt], bp[1][nt], o[1][mt], 0, 0, 0);
            }
    };

    loadK(0, akA);
    for (int jt = 0; jt < JT; jt += 2) {
        loadV(jt);
        if (jt + 1 < JT) loadK(jt + 1, akB);
        compute_tile(akA);
        if (jt + 1 < JT) {
            loadV(jt + 1);
            if (jt + 2 < JT) loadK(jt + 2, akA);
            compute_tile(akB);
        }
    }

    // deferred l reduction across the 4 quads (m is already quad-uniform)
    float l_tot[2];
#pragma unroll
    for (int g = 0; g < 2; ++g) {
        float lv = l[g];
        lv += __shfl_xor(lv, 16, 64);
        lv += __shfl_xor(lv, 32, 64);
        l_tot[g] = lv;
    }

    if (SPLIT > 1) {
        // epilogue: transpose O^T through LDS for coalesced f16 stores
#pragma unroll
        for (int g = 0; g < 2; ++g)
#pragma unroll
            for (int mt = 0; mt < 4; ++mt)
#pragma unroll
                for (int r = 0; r < 4; ++r)
                    tb[(mt * 16 + q4 * 4 + r) * TS + w * 32 + g * 16 + n] =
                        (_Float16)o[g][mt][r];
#pragma unroll
        for (int g = 0; g < 2; ++g) {
            if (q4 == 0) {
                const int ig = i0 + w * 32 + g * 16 + n;
                float2* mlp = (float2*)&ml[((size_t)(b * SPLIT + h) * NVOX + ig) * 2];
                *mlp = make_float2(m_prev[g], l_tot[g]);
            }
        }
        __syncthreads();
        const int cr = t >> 2;                 // 0..63 output channel row
        const int ib = (t & 3) * 32;           // i-chunk base within 128
        const size_t base = ((size_t)(b * SPLIT + h) * 64 + cr) * NVOX + i0 + ib;
#pragma unroll
        for (int u = 0; u < 4; ++u) {
            f16x8 vv = *(const f16x8*)&tb[cr * TS + ib + u * 8];
            *(f16x8*)&po[base + u * 8] = vv;
        }
    } else {
#pragma unroll
        for (int g = 0; g < 2; ++g) {
            const int ig = i0 + w * 32 + g * 16 + n;
            const float inv = 1.0f / l_tot[g];
#pragma unroll
            for (int mt = 0; mt < 4; ++mt)
#pragma unroll
                for (int r = 0; r < 4; ++r)
                    out[(size_t)(b * CCH + mt * 16 + q4 * 4 + r) * NVOX + ig] =
                        o[g][mt][r] * inv;
        }
    }
}

// ---------------- Kernel C: combine split-j partials (f16 partials) ----------------
template <int SPLIT>
__global__ __launch_bounds__(256) void combine(
    const _Float16* __restrict__ po, const float* __restrict__ ml,
    float* __restrict__ out)
{
    __shared__ float wls[SPLIT * 64];
    const int t  = threadIdx.x;
    const int b  = blockIdx.x >> 6;
    const int i0 = (blockIdx.x & 63) * 64;

    if (t < 64) {
        const int i = i0 + t;
        float mv[SPLIT], lv[SPLIT], M = -1e30f;
#pragma unroll
        for (int h = 0; h < SPLIT; ++h) {
            mv[h] = ml[((size_t)(b * SPLIT + h) * NVOX + i) * 2 + 0];
            lv[h] = ml[((size_t)(b * SPLIT + h) * NVOX + i) * 2 + 1];
            M = fmaxf(M, mv[h]);
        }
        float den = 0.f;
#pragma unroll
        for (int h = 0; h < SPLIT; ++h) den += lv[h] * __expf(mv[h] - M);
        const float inv = 1.0f / den;
#pragma unroll
        for (int h = 0; h < SPLIT; ++h) wls[h * 64 + t] = __expf(mv[h] - M) * inv;
    }
    __syncthreads();

    const int c  = t >> 2;
    const int iq = t & 3;
    float acc[16];
#pragma unroll
    for (int u = 0; u < 16; ++u) acc[u] = 0.f;
#pragma unroll
    for (int h = 0; h < SPLIT; ++h) {
        const f16x8* src = (const f16x8*)&po[((size_t)(b * SPLIT + h) * 64 + c) * NVOX + i0 + iq * 16];
        const float* wp  = &wls[h * 64 + iq * 16];
#pragma unroll
        for (int u = 0; u < 2; ++u) {
            f16x8 f = src[u];
#pragma unroll
            for (int e = 0; e < 8; ++e)
                acc[u * 8 + e] = fmaf((float)f[e], wp[u * 8 + e], acc[u * 8 + e]);
        }
    }
    float4* dst = (float4*)&out[(size_t)(b * CCH + c) * NVOX + i0 + iq * 16];
#pragma unroll
    for (int u = 0; u < 4; ++u)
        dst[u] = make_float4(acc[u * 4], acc[u * 4 + 1], acc[u * 4 + 2], acc[u * 4 + 3]);
}

extern "C" void kernel_launch(void* const* d_in, const int* in_sizes, int n_in,
                              void* d_out, int out_size, void* d_ws, size_t ws_size,
                              hipStream_t stream)
{
    const float* x  = (const float*)d_in[0];
    const float* Wq = (const float*)d_in[1];
    const float* bq = (const float*)d_in[2];
    const float* Wk = (const float*)d_in[3];
    const float* bk = (const float*)d_in[4];
    const float* Wv = (const float*)d_in[5];
    const float* bv = (const float*)d_in[6];
    float* out = (float*)d_out;

    _Float16* qh  = (_Float16*)d_ws;                // B*N*C halves
    _Float16* khf = qh + NB * NVOX * CCH;
    _Float16* vhf = khf + NB * NVOX * CCH;
    _Float16* po  = vhf + NB * NVOX * CCH;          // B*SPLIT*64*N halves
    const size_t qkv_bytes = (size_t)3 * NB * NVOX * CCH * sizeof(_Float16);

    qkv_proj<<<NB * (NVOX / 32), 256, 0, stream>>>(x, Wq, bq, Wk, bk, Wv, bv, qh, khf, vhf);

    auto need = [&](int sp) {
        return qkv_bytes + (size_t)NB * sp * 64 * NVOX * sizeof(_Float16)
                         + (size_t)NB * sp * NVOX * 2 * sizeof(float);
    };

    if (ws_size >= need(8)) {
        float* ml = (float*)(po + (size_t)NB * 8 * 64 * NVOX);
        attn<8><<<NB * 32 * 8, 256, 0, stream>>>(qh, khf, vhf, po, ml, out);
        combine<8><<<NB * 64, 256, 0, stream>>>(po, ml, out);
    } else if (ws_size >= need(4)) {
        float* ml = (float*)(po + (size_t)NB * 4 * 64 * NVOX);
        attn<4><<<NB * 32 * 4, 256, 0, stream>>>(qh, khf, vhf, po, ml, out);
        combine<4><<<NB * 64, 256, 0, stream>>>(po, ml, out);
    } else if (ws_size >= need(2)) {
        float* ml = (float*)(po + (size_t)NB * 2 * 64 * NVOX);
        attn<2><<<NB * 32 * 2, 256, 0, stream>>>(qh, khf, vhf, po, ml, out);
        combine<2><<<NB * 64, 256, 0, stream>>>(po, ml, out);
    } else {
        attn<1><<<NB * 32, 256, 0, stream>>>(qh, khf, vhf, nullptr, nullptr, out);
    }
}